// Round 11
// baseline (203.240 us; speedup 1.0000x reference)
//
#include <hip/hip_runtime.h>
#include <math.h>

#define B_   16
#define SQ_  1024
#define SC_  1024
#define D_   768
#define H_   1536

typedef __attribute__((ext_vector_type(4))) float f32x4;
typedef __attribute__((ext_vector_type(8))) short bf16x8;

// packed f32x2 -> bf16x2 (RNE), low16 = bf16(x), high16 = bf16(y)
__device__ __forceinline__ unsigned cvtpk(float x, float y) {
  unsigned r;
  asm("v_cvt_pk_bf16_f32 %0, %1, %2" : "=v"(r) : "v"(x), "v"(y));
  return r;
}

// split 8 floats -> (hi bf16x8, lo bf16x8); lo = x - hi (exactly representable)
__device__ __forceinline__ void split8(float4 r0, float4 r1, bf16x8& h8, bf16x8& l8) {
  unsigned h01 = cvtpk(r0.x, r0.y);
  unsigned h23 = cvtpk(r0.z, r0.w);
  unsigned h45 = cvtpk(r1.x, r1.y);
  unsigned h67 = cvtpk(r1.z, r1.w);
  float f0 = __uint_as_float(h01 << 16), f1 = __uint_as_float(h01 & 0xFFFF0000u);
  float f2 = __uint_as_float(h23 << 16), f3 = __uint_as_float(h23 & 0xFFFF0000u);
  float f4 = __uint_as_float(h45 << 16), f5 = __uint_as_float(h45 & 0xFFFF0000u);
  float f6 = __uint_as_float(h67 << 16), f7 = __uint_as_float(h67 & 0xFFFF0000u);
  unsigned l01 = cvtpk(r0.x - f0, r0.y - f1);
  unsigned l23 = cvtpk(r0.z - f2, r0.w - f3);
  unsigned l45 = cvtpk(r1.x - f4, r1.y - f5);
  unsigned l67 = cvtpk(r1.z - f6, r1.w - f7);
  union U { unsigned u[4]; bf16x8 v; };
  U H; H.u[0] = h01; H.u[1] = h23; H.u[2] = h45; H.u[3] = h67; h8 = H.v;
  U L; L.u[0] = l01; L.u[1] = l23; L.u[2] = l45; L.u[3] = l67; l8 = L.v;
}

// e^s as a double, for s in ~[-200, 200]: 2^frac via exp2f, 2^int via exponent bits
__device__ __forceinline__ double exp_pos(float s) {
  float t = s * 1.4426950408889634f;   // s * log2(e)
  float n = floorf(t);
  float p = exp2f(t - n);              // 2^frac in [1,2)
  long long e = (long long)n;
  double scale = __longlong_as_double((unsigned long long)(e + 1023LL) << 52);
  return (double)p * scale;
}

// ---------------------------------------------------------------------------
// Kernel 0: per (batch, which) mask compaction. Stable prefix-sum scan.
// ---------------------------------------------------------------------------
__global__ __launch_bounds__(256) void compact_kernel(
    const int* __restrict__ mask_q, const int* __restrict__ mask_c,
    int* __restrict__ idx_q, int* __restrict__ idx_c, int* __restrict__ cnt)
{
  int which = blockIdx.x & 1;   // 0: q, 1: c
  int b     = blockIdx.x >> 1;
  const int* m = (which ? mask_c : mask_q) + b * 1024;
  int* idx     = (which ? idx_c : idx_q) + b * 1024;

  __shared__ int tsum[256];
  int t = threadIdx.x;
  int v[4], s = 0;
#pragma unroll
  for (int e = 0; e < 4; ++e) { v[e] = (m[t * 4 + e] != 0) ? 1 : 0; s += v[e]; }
  tsum[t] = s;
  __syncthreads();
  for (int off = 1; off < 256; off <<= 1) {
    int add = (t >= off) ? tsum[t - off] : 0;
    __syncthreads();
    tsum[t] += add;
    __syncthreads();
  }
  int pos = tsum[t] - s;   // exclusive prefix
#pragma unroll
  for (int e = 0; e < 4; ++e) {
    if (v[e]) idx[pos++] = t * 4 + e;
  }
  if (t == 255) cnt[b * 2 + which] = tsum[255];
}

// ---------------------------------------------------------------------------
// Kernel 0b: tile bookkeeping (128x128 tiles now).
// tmeta[0]=total tiles, [1+b]=tile offset of batch b, [17+b]=ntc_b
// ---------------------------------------------------------------------------
__global__ void tile_setup_kernel(const int* __restrict__ cnt, int* __restrict__ tmeta)
{
  if (threadIdx.x == 0) {
    int off = 0;
    for (int b = 0; b < B_; ++b) {
      int ntq = (cnt[2 * b] + 127) >> 7;
      int ntc = (cnt[2 * b + 1] + 127) >> 7;
      tmeta[1 + b]  = off;
      tmeta[17 + b] = ntc;
      off += ntq * ntc;
    }
    tmeta[0] = off;
  }
}

// ---------------------------------------------------------------------------
// Kernel 1: LDS-FREE compact GEMM. Block = 128x128 tile = 2x2 waves of 64x64.
// Each wave loads A/B MFMA fragments DIRECTLY from global (lane reads 8
// consecutive k-floats of its row), splits fp32->hi/lo bf16 in registers.
// No LDS, no barriers, no bank conflicts. Waves beyond extent exit freely.
// Epilogue: S store + exp-domain R/C sums via shfl + atomics.
// ---------------------------------------------------------------------------
__global__ __launch_bounds__(256, 1) void gemm_mfma_kernel(
    const float* __restrict__ q, const float* __restrict__ c,
    const int* __restrict__ idx_q, const int* __restrict__ idx_c,
    const int* __restrict__ cnt, const int* __restrict__ tmeta,
    float* __restrict__ S, double* __restrict__ R, double* __restrict__ C)
{
  const int flat  = blockIdx.x;
  const int total = tmeta[0];
  if (flat >= total) return;

  const int t    = threadIdx.x;
  const int lane = t & 63;
  const int w    = t >> 6;            // 0..3 -> 2x2 sub-tiles

  // decode tile -> (bb, ty, tx) at 128 granularity
  int bb = 0;
#pragma unroll
  for (int k = 1; k < 16; ++k) bb += (flat >= tmeta[1 + k]) ? 1 : 0;
  const int rem = flat - tmeta[1 + bb];
  const int ntc = tmeta[17 + bb];
  const int ty  = rem / ntc;
  const int tx  = rem - ty * ntc;
  const int nq  = cnt[2 * bb], nc = cnt[2 * bb + 1];

  const int i0 = ty * 128 + (w >> 1) * 64;
  const int j0 = tx * 128 + (w & 1) * 64;
  if (i0 >= nq || j0 >= nc) return;   // per-wave exit: NO barriers anywhere

  const int fr = lane & 15;           // fragment row (A) / col (B)
  const int fq = lane >> 4;           // k-group: k = fq*8 + e

  // per-fragment global base pointers (gathered rows, + fq*8 k offset)
  const float* aP[4];
  const float* bP[4];
#pragma unroll
  for (int m = 0; m < 4; ++m) {
    int r = idx_q[bb * 1024 + min(i0 + m * 16 + fr, nq - 1)];
    aP[m] = q + ((size_t)bb * SQ_ + r) * D_ + fq * 8;
  }
#pragma unroll
  for (int n = 0; n < 4; ++n) {
    int cc = idx_c[bb * 1024 + min(j0 + n * 16 + fr, nc - 1)];
    bP[n] = c + ((size_t)bb * SC_ + cc) * D_ + fq * 8;
  }

  f32x4 acc[4][4] = {};
  float4 aRaw[4][2], bRaw[4][2];
#pragma unroll
  for (int m = 0; m < 4; ++m) {
    aRaw[m][0] = *(const float4*)(aP[m]);
    aRaw[m][1] = *(const float4*)(aP[m] + 4);
  }
#pragma unroll
  for (int n = 0; n < 4; ++n) {
    bRaw[n][0] = *(const float4*)(bP[n]);
    bRaw[n][1] = *(const float4*)(bP[n] + 4);
  }

  for (int k0 = 0; k0 < D_; k0 += 32) {
    bf16x8 aH[4], aL[4], bH[4], bL[4];
#pragma unroll
    for (int m = 0; m < 4; ++m) split8(aRaw[m][0], aRaw[m][1], aH[m], aL[m]);
#pragma unroll
    for (int n = 0; n < 4; ++n) split8(bRaw[n][0], bRaw[n][1], bH[n], bL[n]);

    const int nk = k0 + 32;
    if (nk < D_) {   // prefetch next k-chunk; flies during MFMA below
#pragma unroll
      for (int m = 0; m < 4; ++m) {
        aRaw[m][0] = *(const float4*)(aP[m] + nk);
        aRaw[m][1] = *(const float4*)(aP[m] + nk + 4);
      }
#pragma unroll
      for (int n = 0; n < 4; ++n) {
        bRaw[n][0] = *(const float4*)(bP[n] + nk);
        bRaw[n][1] = *(const float4*)(bP[n] + nk + 4);
      }
    }

#pragma unroll
    for (int n = 0; n < 4; ++n)
#pragma unroll
      for (int m = 0; m < 4; ++m) {
        acc[m][n] = __builtin_amdgcn_mfma_f32_16x16x32_bf16(aH[m], bH[n], acc[m][n], 0, 0, 0);
        acc[m][n] = __builtin_amdgcn_mfma_f32_16x16x32_bf16(aH[m], bL[n], acc[m][n], 0, 0, 0);
        acc[m][n] = __builtin_amdgcn_mfma_f32_16x16x32_bf16(aL[m], bH[n], acc[m][n], 0, 0, 0);
      }
  }

  // ---- epilogue: S store + exp-domain R/C (all-shfl, no LDS) ----
  double rowPart[4][4];
#pragma unroll
  for (int m = 0; m < 4; ++m)
#pragma unroll
    for (int rr = 0; rr < 4; ++rr) rowPart[m][rr] = 0.0;
  double colSum[4] = {0.0, 0.0, 0.0, 0.0};

#pragma unroll
  for (int m = 0; m < 4; ++m) {
    const int rbase = i0 + m * 16 + fq * 4;
#pragma unroll
    for (int n = 0; n < 4; ++n) {
      const int col = j0 + n * 16 + fr;
      const bool cok = (col < nc);
      float* Sp = S + ((size_t)bb * SQ_ + rbase) * SC_ + col;
#pragma unroll
      for (int rr = 0; rr < 4; ++rr) {
        float v = acc[m][n][rr];
        bool valid = ((rbase + rr) < nq) && cok && (v != 0.f);
        Sp[(size_t)rr * SC_] = valid ? v : -INFINITY;
        double e = valid ? exp_pos(v) : 0.0;
        colSum[n] += e;
        rowPart[m][rr] += e;
      }
    }
  }
  // row sums: reduce across fr (xor<=8 stays within 16-lane group)
#pragma unroll
  for (int m = 0; m < 4; ++m)
#pragma unroll
    for (int rr = 0; rr < 4; ++rr) {
      double x = rowPart[m][rr];
      x += __shfl_xor(x, 1); x += __shfl_xor(x, 2);
      x += __shfl_xor(x, 4); x += __shfl_xor(x, 8);
      rowPart[m][rr] = x;
    }
  if (fr == 0) {
#pragma unroll
    for (int m = 0; m < 4; ++m)
#pragma unroll
      for (int rr = 0; rr < 4; ++rr) {
        double x = rowPart[m][rr];
        if (x != 0.0) atomicAdd(&R[bb * SQ_ + i0 + m * 16 + fq * 4 + rr], x);
      }
  }
  // col sums: reduce across fq (xor 16, 32)
#pragma unroll
  for (int n = 0; n < 4; ++n) {
    double x = colSum[n];
    x += __shfl_xor(x, 16); x += __shfl_xor(x, 32);
    if (fq == 0 && x != 0.0) atomicAdd(&C[bb * SC_ + j0 + n * 16 + fr], x);
  }
}

// ---------------------------------------------------------------------------
// Kernel 2: single pass over S -> cp[j] = sum_i e^{s-lnR_i} and
// rpp[i] = sum_j e^{s-lnC_j}. 64-col strip per block, 16 waves over rows.
// ---------------------------------------------------------------------------
__global__ __launch_bounds__(1024) void pass2_kernel(
    const float* __restrict__ S, const int* __restrict__ cnt,
    const double* __restrict__ R, const double* __restrict__ C,
    float* __restrict__ cp, float* __restrict__ rpp)
{
  __shared__ float lnR_lds[SQ_];
  __shared__ float red[16][64];

  int b  = blockIdx.y;
  int j0 = blockIdx.x * 64;
  int nq_pad = (cnt[2 * b] + 63) & ~63;
  int nc_pad = (cnt[2 * b + 1] + 63) & ~63;
  if (j0 >= nc_pad) return;        // block-uniform exit before barriers
  int t = threadIdx.x;

  if (t < nq_pad) {
    double Ri = R[b * SQ_ + t];
    lnR_lds[t] = (Ri > 0.0) ? (float)log(Ri) : INFINITY;
  }
  __syncthreads();

  int lane = t & 63, wv = t >> 6;
  int j = j0 + lane;
  double Cj = C[b * SC_ + j];
  float lnCj = (Cj > 0.0) ? (float)log(Cj) : INFINITY;

  int chunk = nq_pad >> 4;          // rows per wave
  int i0 = wv * chunk;
  const float* Sb = S + ((size_t)b * SQ_ + i0) * SC_ + j;

  float cpAcc = 0.f;
  for (int ii = 0; ii < chunk; ++ii) {
    int i = i0 + ii;
    float v = Sb[(size_t)ii * SC_];
    cpAcc += __expf(v - lnR_lds[i]);
    float e2 = __expf(v - lnCj);
#pragma unroll
    for (int o = 32; o; o >>= 1) e2 += __shfl_xor(e2, o);
    if (lane == 0) atomicAdd(&rpp[b * SQ_ + i], e2);
  }

  red[wv][lane] = cpAcc;
  __syncthreads();
  if (t < 64) {
    float s = 0.f;
#pragma unroll
    for (int k = 0; k < 16; ++k) s += red[k][t];
    cp[b * SC_ + j0 + t] = s;
  }
}

// ---------------------------------------------------------------------------
// Kernel 5: combine partials over VALID rows via idx gather; atomicAdd into X.
// ---------------------------------------------------------------------------
__global__ __launch_bounds__(256) void combine_kernel(
    const float* __restrict__ q, const float* __restrict__ c,
    const int* __restrict__ idx_q, const int* __restrict__ idx_c,
    const int* __restrict__ cnt,
    const float* __restrict__ cp, const float* __restrict__ rpp,
    float* __restrict__ X)
{
  int jc = blockIdx.x;   // 0..31
  int op = blockIdx.y;   // 0: c/cp ; 1: q/rpp
  int b  = blockIdx.z;
  int t  = threadIdx.x;

  int n = op ? cnt[2 * b] : cnt[2 * b + 1];
  const float* src = op ? (q + (size_t)b * SQ_ * D_) : (c + (size_t)b * SC_ * D_);
  const float* wv  = op ? (rpp + b * SQ_) : (cp + b * SC_);
  const int*   idx = (op ? idx_q : idx_c) + b * 1024;

  float a0 = 0.f, a1 = 0.f, a2 = 0.f;
  int je = min(jc * 32 + 32, n);
  for (int j = jc * 32; j < je; ++j) {
    float wj = wv[j];
    const float* r = src + (size_t)idx[j] * D_;
    a0 += wj * r[t];
    a1 += wj * r[t + 256];
    a2 += wj * r[t + 512];
  }
  float* xp = X + (size_t)b * H_ + op * D_;
  atomicAdd(&xp[t], a0);
  atomicAdd(&xp[t + 256], a1);
  atomicAdd(&xp[t + 512], a2);
}

// ---------------------------------------------------------------------------
// Kernel 7: fc1. One wave per h; W1 row in registers, loop over 16 batches.
// ---------------------------------------------------------------------------
__global__ __launch_bounds__(256) void fc1_kernel(
    const float* __restrict__ X, const float* __restrict__ W1,
    const float* __restrict__ b1, float* __restrict__ Y)
{
  int w = threadIdx.x >> 6, lane = threadIdx.x & 63;
  int h = blockIdx.x * 4 + w;           // 0..1535
  const float4* wr = (const float4*)(W1 + (size_t)h * H_);
  float4 wv[6];
#pragma unroll
  for (int it = 0; it < 6; ++it) wv[it] = wr[it * 64 + lane];
  float bias = b1[h];

  for (int b = 0; b < B_; ++b) {
    const float4* x = (const float4*)(X + (size_t)b * H_);
    float accv = 0.f;
#pragma unroll
    for (int it = 0; it < 6; ++it) {
      float4 xv = x[it * 64 + lane];
      accv += xv.x * wv[it].x + xv.y * wv[it].y + xv.z * wv[it].z + xv.w * wv[it].w;
    }
#pragma unroll
    for (int o = 32; o; o >>= 1) accv += __shfl_xor(accv, o);
    if (lane == 0) Y[(size_t)b * H_ + h] = tanhf(accv + bias);
  }
}

// ---------------------------------------------------------------------------
// Kernel 8: fc2 + log_softmax + NLL loss.
// ---------------------------------------------------------------------------
__global__ __launch_bounds__(64) void fc2_loss_kernel(
    const float* __restrict__ Y, const float* __restrict__ W2,
    const float* __restrict__ b2, const int* __restrict__ labels,
    float* __restrict__ out)
{
  __shared__ float logp_s[B_][2];
  int t = threadIdx.x;
  if (t < 2 * B_) {
    int b = t >> 1, n = t & 1;
    const float* y = Y + (size_t)b * H_;
    const float* w = W2 + (size_t)n * H_;
    float accv = b2[n];
    for (int k = 0; k < H_; ++k) accv += y[k] * w[k];
    logp_s[b][n] = accv;
  }
  __syncthreads();
  if (t < B_) {
    float l0 = logp_s[t][0], l1 = logp_s[t][1];
    float m = fmaxf(l0, l1);
    float lse = m + logf(expf(l0 - m) + expf(l1 - m));
    logp_s[t][0] = l0 - lse;
    logp_s[t][1] = l1 - lse;
  }
  __syncthreads();
  if (t < 2 * B_) out[1 + t] = logp_s[t >> 1][t & 1];
  if (t == 0) {
    float loss = 0.f;
    for (int b = 0; b < B_; ++b) loss -= logp_s[b][labels[b]];
    out[0] = loss / (float)B_;
  }
}

// ---------------------------------------------------------------------------
extern "C" void kernel_launch(void* const* d_in, const int* in_sizes, int n_in,
                              void* d_out, int out_size, void* d_ws, size_t ws_size,
                              hipStream_t stream) {
  const float* q      = (const float*)d_in[0];
  const float* c      = (const float*)d_in[1];
  const int*   mask_q = (const int*)d_in[2];
  const int*   mask_c = (const int*)d_in[3];
  const int*   labels = (const int*)d_in[4];
  const float* W1     = (const float*)d_in[5];
  const float* b1     = (const float*)d_in[6];
  const float* W2     = (const float*)d_in[7];
  const float* b2     = (const float*)d_in[8];
  float* out = (float*)d_out;

  float*  ws   = (float*)d_ws;
  float*  S    = ws;                                  // 16M floats (64 MiB)
  double* R    = (double*)(ws + (size_t)B_ * SQ_ * SC_); // 16K doubles
  double* C    = R + B_ * SQ_;                        // 16K doubles
  float*  cp   = (float*)(C + B_ * SC_);              // 16K floats
  float*  rpp  = cp + B_ * SC_;                       // 16K floats
  int*    cnt  = (int*)(rpp + B_ * SQ_);              // 32 ints
  int*    tmeta = cnt + 2 * B_;                       // 34 ints
  int*    idx_q = tmeta + 34;
  int*    idx_c = idx_q + B_ * SQ_;
  // X/Y overlay S (S dead after pass2)
  float*  X    = ws;                                  // 16*1536
  float*  Y    = ws + B_ * H_;                        // 16*1536

  // zero R, C, cp, rpp in one contiguous memset (384 KB)
  (void)hipMemsetAsync((void*)R, 0, (size_t)(2 * B_ * SQ_) * sizeof(double)
                              + (size_t)(2 * B_ * SC_) * sizeof(float), stream);

  compact_kernel<<<2 * B_, 256, 0, stream>>>(mask_q, mask_c, idx_q, idx_c, cnt);
  tile_setup_kernel<<<1, 64, 0, stream>>>(cnt, tmeta);

  gemm_mfma_kernel<<<1024, 256, 0, stream>>>(q, c, idx_q, idx_c, cnt, tmeta, S, R, C);

  pass2_kernel<<<dim3(SC_ / 64, B_), 1024, 0, stream>>>(S, cnt, R, C, cp, rpp);

  (void)hipMemsetAsync((void*)X, 0, (size_t)B_ * H_ * sizeof(float), stream);
  combine_kernel<<<dim3(32, 2, B_), 256, 0, stream>>>(q, c, idx_q, idx_c, cnt,
                                                      cp, rpp, X);
  fc1_kernel<<<H_ / 4, 256, 0, stream>>>(X, W1, b1, Y);
  fc2_loss_kernel<<<1, 64, 0, stream>>>(Y, W2, b2, labels, out);
}